// Round 4
// baseline (185.595 us; speedup 1.0000x reference)
//
#include <hip/hip_runtime.h>
#include <stdint.h>

// ---------------------------------------------------------------------------
// Problem constants
// ---------------------------------------------------------------------------
#define NSEQ 512        // B*N
#define HIDN 128

// ws byte offsets
#define OFF_PWIH_E 0
#define OFF_PWHH_E (OFF_PWIH_E + 32*512*4)      //  65536
#define OFF_PWIH_D (OFF_PWHH_E + 64*512*4)      // 196608
#define OFF_PWHH_D (OFF_PWIH_D + 64*512*4)      // 327680
#define OFF_BIAS_E (OFF_PWHH_D + 64*512*4)      // 458752
#define OFF_BIAS_D (OFF_BIAS_E + 512*4)         // 460800
#define OFF_W1P    (OFF_BIAS_D + 512*4)         // 462848  conv w1 f16 pairs [288][64]
#define OFF_W2P    (OFF_W1P + 288*64*4)         // 536576  conv w2 f16 pairs [32][64]
#define OFF_FLAT   (OFF_W2P + 32*64*4)          // 544768  [16384] int
#define OFF_W1H    (OFF_FLAT + 16384*4)         // 610304  head W1 f16 pairs [64][64]
#define OFF_DOTS   (1024*1024)                  // [32][512][64] f16 = 2 MB
#define OFF_XT     (4*1024*1024)                // xT [16][128][128][64] f16 = 33.5 MB
#define OFF_GX_FB  (3*1024*1024)                // fallback gx area (no-xT path)
#define GX_BYTES   ((size_t)16384*512*2)        // 16.8 MB
#define WS_NEED_XT ((size_t)(4*1024*1024) + (size_t)16*128*128*64*2 + 1024)

typedef _Float16 h2f __attribute__((ext_vector_type(2)));

static __device__ __forceinline__ h2f u2h(uint32_t u) {
  union { uint32_t u; h2f h; } v; v.u = u; return v.h;
}

#if __has_builtin(__builtin_amdgcn_fdot2)
static __device__ __forceinline__ float fdot2_(uint32_t a, uint32_t b, float c) {
  return __builtin_amdgcn_fdot2(u2h(a), u2h(b), c, false);
}
#else
static __device__ __forceinline__ float fdot2_(uint32_t a, uint32_t b, float c) {
  h2f x = u2h(a), y = u2h(b);
  return c + (float)x.x * (float)y.x + (float)x.y * (float)y.y;
}
#endif

static __device__ __forceinline__ uint32_t packh(float a, float b) {
  union { _Float16 h[2]; uint32_t u; } v;
  v.h[0] = (_Float16)a; v.h[1] = (_Float16)b; return v.u;
}
static __device__ __forceinline__ float sig_(float x) {
  return 1.0f / (1.0f + __expf(-x));
}
static __device__ __forceinline__ float tanh_(float x) {
  return 1.0f - 2.0f / (1.0f + __expf(2.0f * x));
}

// ---------------------------------------------------------------------------
// Kernel 0: weight prep (transpose + f16 pack + bias sums)
// ---------------------------------------------------------------------------
__global__ __launch_bounds__(256) void prep_kernel(
    const float* Wih_e, const float* Whh_e,
    const float* bih_e, const float* bhh_e,
    const float* Wih_d, const float* Whh_d,
    const float* bih_d, const float* bhh_d,
    const float* w1, const float* w2, const float* W1, char* ws, int w1_order) {
  uint32_t* pWih_e = (uint32_t*)(ws + OFF_PWIH_E);
  uint32_t* pWhh_e = (uint32_t*)(ws + OFF_PWHH_E);
  uint32_t* pWih_d = (uint32_t*)(ws + OFF_PWIH_D);
  uint32_t* pWhh_d = (uint32_t*)(ws + OFF_PWHH_D);
  float*    bias_e = (float*)(ws + OFF_BIAS_E);
  float*    bias_d = (float*)(ws + OFF_BIAS_D);
  uint32_t* w1p    = (uint32_t*)(ws + OFF_W1P);
  uint32_t* w2p    = (uint32_t*)(ws + OFF_W2P);
  uint32_t* W1h    = (uint32_t*)(ws + OFF_W1H);

  int idx = blockIdx.x * 256 + threadIdx.x;
  if (idx < 32*512) {                             // pWih_e [k2][g], in=64
    int k2 = idx >> 9, g = idx & 511;
    pWih_e[idx] = packh(Wih_e[g*64 + 2*k2], Wih_e[g*64 + 2*k2 + 1]);
    return;
  }
  idx -= 32*512;
  if (idx < 64*512) {                             // pWhh_e, in=128
    int k2 = idx >> 9, g = idx & 511;
    pWhh_e[idx] = packh(Whh_e[g*128 + 2*k2], Whh_e[g*128 + 2*k2 + 1]);
    return;
  }
  idx -= 64*512;
  if (idx < 64*512) {                             // pWih_d, in=128
    int k2 = idx >> 9, g = idx & 511;
    pWih_d[idx] = packh(Wih_d[g*128 + 2*k2], Wih_d[g*128 + 2*k2 + 1]);
    return;
  }
  idx -= 64*512;
  if (idx < 64*512) {                             // pWhh_d, in=128
    int k2 = idx >> 9, g = idx & 511;
    pWhh_d[idx] = packh(Whh_d[g*128 + 2*k2], Whh_d[g*128 + 2*k2 + 1]);
    return;
  }
  idx -= 64*512;
  if (idx < 512) { bias_e[idx] = bih_e[idx] + bhh_e[idx]; return; }
  idx -= 512;
  if (idx < 512) { bias_d[idx] = bih_d[idx] + bhh_d[idx]; return; }
  idx -= 512;
  if (idx < 288*64) {                             // conv w1 pairs [i2][c]
    int i2 = idx >> 6, c = idx & 63;
    if (w1_order) {
      int tap = i2 >> 5, cin = (i2 & 31) * 2;     // i2 = tap*32 + c2
      w1p[idx] = packh(w1[c*576 + cin*9 + tap], w1[c*576 + (cin+1)*9 + tap]);
    } else {
      w1p[idx] = packh(w1[c*576 + 2*i2], w1[c*576 + 2*i2 + 1]);
    }
    return;
  }
  idx -= 288*64;
  if (idx < 32*64) {                              // conv w2 pairs [c2][d]
    int c2 = idx >> 6, d = idx & 63;
    w2p[idx] = packh(w2[d*64 + 2*c2], w2[d*64 + 2*c2 + 1]);
    return;
  }
  idx -= 32*64;
  if (idx < 64*64) {                              // head W1 pairs [k2][j]
    int k2 = idx >> 6, j = idx & 63;
    W1h[idx] = packh(W1[j*128 + 2*k2], W1[j*128 + 2*k2 + 1]);
    return;
  }
}
#define PREP_TOTAL (32*512 + 3*64*512 + 512 + 512 + 288*64 + 32*64 + 64*64)

// ---------------------------------------------------------------------------
// Kernel 1: point math -> gt (output 1) + flat indices
// ---------------------------------------------------------------------------
__global__ __launch_bounds__(256) void points_kernel(
    const float* mask_point, float* out_gt, int* flat) {
  int p = blockIdx.x * 256 + threadIdx.x;
  if (p >= 16384) return;
  float mx = mask_point[p*2 + 0];
  float my = mask_point[p*2 + 1];
  float fx = fminf(mx * 0.25f, 127.0f);
  float fy = fminf(my * 0.25f, 127.0f);
  out_gt[p*2 + 0] = fx * 4.0f;
  out_gt[p*2 + 1] = fy * 4.0f;
  flat[p] = (int)(__fmaf_rn(fy, 128.0f, fx));   // fy*128 exact -> fma == mul+add
}

// ---------------------------------------------------------------------------
// Kernel T: x [16][64][128][128] f32 -> xT [16][128][128][64] f16 (NHWC)
// ---------------------------------------------------------------------------
__global__ __launch_bounds__(256, 2) void transpose_kernel(
    const float* x, uint32_t* xT32) {
  __shared__ float lds[64][257];
  int bid = blockIdx.x;           // 1024 = 16 b x 16 yt x 4 xt
  int xt = bid & 3, yt = (bid >> 2) & 15, b = bid >> 6;
  int x0 = xt * 32, y0 = yt * 8;
  int tx = threadIdx.x & 31, ty = threadIdx.x >> 5;
  #pragma unroll 8
  for (int c = 0; c < 64; ++c)
    lds[c][ty*32 + tx] = x[((b*64 + c)*128 + (y0 + ty))*128 + (x0 + tx)];
  __syncthreads();
  #pragma unroll 8
  for (int r = 0; r < 32; ++r) {
    int i = threadIdx.x + 256*r;    // i = pos*32 + c2
    int c2 = i & 31, pos = i >> 5;
    int yy = pos >> 5, xx = pos & 31;
    float lo = lds[2*c2][yy*32 + xx], hi = lds[2*c2 + 1][yy*32 + xx];
    xT32[((b*128 + y0 + yy)*128 + (x0 + xx))*32 + c2] = packh(lo, hi);
  }
}

// ---------------------------------------------------------------------------
// Kernel 2: fused gathered conv (3x3 -> ReLU -> 1x1) at points, 4 pts/group
// ---------------------------------------------------------------------------
template <int MODE>
__global__ __launch_bounds__(256, 2) void conv_gather_kernel(
    const float* x, const uint32_t* xT32, const int* point_mask,
    const float* conv1_b, const float* conv2_b,
    const char* ws_ro, _Float16* dots_h, const int* flat) {
  __shared__ uint32_t w1s[64*291];    // 74496 B
  __shared__ uint32_t patch2[4*288];  //  4608 B
  __shared__ uint32_t tl2[4*32];      //   512 B

  const uint32_t* w1p = (const uint32_t*)(ws_ro + OFF_W1P);
  const uint32_t* w2p = (const uint32_t*)(ws_ro + OFF_W2P);
  int tid = threadIdx.x;
  for (int i = tid; i < 288*64; i += 256) {
    int i2 = i >> 6, cc = i & 63;
    w1s[cc*291 + i2] = w1p[i];
  }

  int q = tid >> 6, c = tid & 63;
  float c1b = conv1_b[c], c2b = conv2_b[c];

  for (int g = 0; g < 8; ++g) {
    int p0 = blockIdx.x * 32 + g * 4;
    __syncthreads();
    if (MODE == 1) {
      #pragma unroll
      for (int r = 0; r < 5; ++r) {  // 1152 u32 = 4 pts x 288
        int u = tid + 256*r;
        if (u < 1152) {
          int slot = u / 288, w = u - slot*288;
          int tap = w >> 5, c2i = w & 31;
          int p = p0 + slot;
          int fl = flat[p];
          int hh = fl >> 7, ww = fl & 127;
          int b = p >> 10;
          int dy = tap / 3, dx = tap - dy*3;
          int yy = hh + dy - 1, xx = ww + dx - 1;
          uint32_t v = 0u;
          if (yy >= 0 && yy < 128 && xx >= 0 && xx < 128)
            v = xT32[((b*128 + yy)*128 + xx)*32 + c2i];
          patch2[slot*288 + w] = v;
        }
      }
    } else {
      #pragma unroll
      for (int r = 0; r < 9; ++r) {  // 2304 halves = 4 pts x 576
        int l = tid + 256*r;
        int slot = l / 576;
        int within = l - slot*576;
        int cp = within / 9;
        int tap = within - cp*9;
        int p = p0 + slot;
        int fl = flat[p];
        int hh = fl >> 7, ww = fl & 127;
        int b = p >> 10;
        int yy = hh + tap/3 - 1, xx = ww + tap%3 - 1;
        float v = 0.0f;
        if (yy >= 0 && yy < 128 && xx >= 0 && xx < 128)
          v = x[((b*64 + cp)*128 + yy)*128 + xx];
        ((_Float16*)patch2)[l] = (_Float16)v;
      }
    }
    __syncthreads();

    float a0 = c1b, a1 = 0.f, a2 = 0.f, a3 = 0.f;
    int cbase = c * 291, pbase = q * 288;
    #pragma unroll 4
    for (int i2 = 0; i2 < 288; i2 += 4) {
      a0 = fdot2_(w1s[cbase + i2+0], patch2[pbase + i2+0], a0);
      a1 = fdot2_(w1s[cbase + i2+1], patch2[pbase + i2+1], a1);
      a2 = fdot2_(w1s[cbase + i2+2], patch2[pbase + i2+2], a2);
      a3 = fdot2_(w1s[cbase + i2+3], patch2[pbase + i2+3], a3);
    }
    float t1 = fmaxf((a0 + a1) + (a2 + a3), 0.0f);
    ((_Float16*)tl2)[q*64 + c] = (_Float16)t1;
    // tl2[q] written/read by same wave -> no barrier

    float acc2 = c2b;
    #pragma unroll
    for (int c2i = 0; c2i < 32; ++c2i)
      acc2 = fdot2_(w2p[c2i*64 + c], tl2[q*32 + c2i], acc2);
    int p = p0 + q;
    acc2 *= (float)point_mask[p];
    int k = p & 31, bn = p >> 5;
    dots_h[(k*NSEQ + bn)*64 + c] = (_Float16)acc2;   // time-major [k][bn][d]
  }
}

// ---------------------------------------------------------------------------
// Kernel G: encoder x-projection GEMM: gx[R][g] = bias_e[g] + Wih_e . dots[R]
// R = t*512 + bn (16384 rows). 512 blocks x 512 threads, 32 rows/block.
// ---------------------------------------------------------------------------
__global__ __launch_bounds__(512, 4) void gx_gemm_kernel(
    const char* ws_ro, _Float16* gx) {
  const uint32_t* pWih_e = (const uint32_t*)(ws_ro + OFF_PWIH_E);
  const float*    bias_e = (const float*)(ws_ro + OFF_BIAS_E);
  const uint32_t* dots_u = (const uint32_t*)(ws_ro + OFF_DOTS);
  __shared__ uint32_t xs[32][32];   // 4 KB: 32 rows x 32 f16-pairs
  int tid = threadIdx.x;
  int R0 = blockIdx.x * 32;
  for (int i = tid; i < 32*32; i += 512)
    xs[i >> 5][i & 31] = dots_u[(R0 + (i >> 5))*32 + (i & 31)];
  uint32_t wv[32];
  #pragma unroll
  for (int k = 0; k < 32; ++k) wv[k] = pWih_e[k*512 + tid];
  float bs = bias_e[tid];
  __syncthreads();
  #pragma unroll 2
  for (int r = 0; r < 32; ++r) {
    float a = bs;
    #pragma unroll
    for (int k = 0; k < 32; ++k) a = fdot2_(wv[k], xs[r][k], a);
    gx[(size_t)(R0 + r)*512 + tid] = (_Float16)a;
  }
}

// ---------------------------------------------------------------------------
// Kernel 3: recurrent LSTMs + batched MLP head.
// 256 blocks x 1024 threads (16 waves, <=128 VGPR -> true register pinning).
// thread = (gate g in 0..511, k-half hf in 0..1); 2 sequences/block.
// Encoder x-projection comes precomputed from gx.
// ---------------------------------------------------------------------------
__global__ __launch_bounds__(1024, 4) void lstm_head_kernel(
    const char* ws_ro, const _Float16* gx,
    const float* b1, const float* W2, const float* b2,
    float* out_kp) {
  const uint32_t* pWhh_e = (const uint32_t*)(ws_ro + OFF_PWHH_E);
  const uint32_t* pWih_d = (const uint32_t*)(ws_ro + OFF_PWIH_D);
  const uint32_t* pWhh_d = (const uint32_t*)(ws_ro + OFF_PWHH_D);
  const float*    bias_d = (const float*)(ws_ro + OFF_BIAS_D);
  const uint32_t* W1h    = (const uint32_t*)(ws_ro + OFF_W1H);

  __shared__ uint32_t enc2[2][32][64];    // 16 KB (enc h, f16 pairs)
  __shared__ uint32_t dech2[2][32][64];   // 16 KB (dec h, f16 pairs)
  __shared__ uint32_t hb2[2][64];         // 512 B (current h, f16 pairs)
  __shared__ float    part[2][2][512];    //  8 KB ([seq][half][gate])
  __shared__ float    hidf[64][65];       // 16.6 KB

  int tid = threadIdx.x;
  int g = tid & 511, hf = tid >> 9;
  int kb = hf * 32;                       // k-pair base for this half
  int bn0 = blockIdx.x * 2;

  uint32_t wa[32], wb[32];
  #pragma unroll
  for (int k = 0; k < 32; ++k) wa[k] = pWhh_e[(kb + k)*512 + g];

  if (tid < 128) hb2[tid >> 6][tid & 63] = 0u;
  float c_reg = 0.0f;
  __syncthreads();

  // ----------------- encoder (h-recurrence only; x-part from gx) ----------
  for (int t = 0; t < 32; ++t) {
    float a0, a1;
    if (hf == 0) {
      a0 = (float)gx[(size_t)(t*512 + bn0 + 0)*512 + g];
      a1 = (float)gx[(size_t)(t*512 + bn0 + 1)*512 + g];
    } else { a0 = 0.f; a1 = 0.f; }
    #pragma unroll
    for (int k = 0; k < 32; ++k) {
      a0 = fdot2_(wa[k], hb2[0][kb + k], a0);
      a1 = fdot2_(wa[k], hb2[1][kb + k], a1);
    }
    part[0][hf][g] = a0;
    part[1][hf][g] = a1;
    __syncthreads();
    if (tid < 256) {
      int s = tid >> 7, u = tid & 127;
      float ig = sig_ (part[s][0][u]       + part[s][1][u]);
      float fg = sig_ (part[s][0][128 + u] + part[s][1][128 + u]);
      float gg = tanh_(part[s][0][256 + u] + part[s][1][256 + u]);
      float og = sig_ (part[s][0][384 + u] + part[s][1][384 + u]);
      c_reg = fg * c_reg + ig * gg;
      float hh = og * tanh_(c_reg);
      _Float16 hv = (_Float16)hh;
      ((_Float16*)&hb2[s][0])[u] = hv;
      ((_Float16*)&enc2[s][t][0])[u] = hv;
    }
    __syncthreads();
  }

  // ----------------- decoder -----------------
  #pragma unroll
  for (int k = 0; k < 32; ++k) {
    wa[k] = pWih_d[(kb + k)*512 + g];
    wb[k] = pWhh_d[(kb + k)*512 + g];
  }
  float bd = (hf == 0) ? bias_d[g] : 0.0f;

  for (int t = 0; t < 32; ++t) {
    float a0 = bd, a1 = bd;
    #pragma unroll
    for (int k = 0; k < 32; ++k) {
      a0 = fdot2_(wa[k], enc2[0][t][kb + k], a0);
      a1 = fdot2_(wa[k], enc2[1][t][kb + k], a1);
    }
    #pragma unroll
    for (int k = 0; k < 32; ++k) {
      a0 = fdot2_(wb[k], hb2[0][kb + k], a0);
      a1 = fdot2_(wb[k], hb2[1][kb + k], a1);
    }
    part[0][hf][g] = a0;
    part[1][hf][g] = a1;
    __syncthreads();
    if (tid < 256) {
      int s = tid >> 7, u = tid & 127;
      float ig = sig_ (part[s][0][u]       + part[s][1][u]);
      float fg = sig_ (part[s][0][128 + u] + part[s][1][128 + u]);
      float gg = tanh_(part[s][0][256 + u] + part[s][1][256 + u]);
      float og = sig_ (part[s][0][384 + u] + part[s][1][384 + u]);
      c_reg = fg * c_reg + ig * gg;
      float hh = og * tanh_(c_reg);
      _Float16 hv = (_Float16)hh;
      ((_Float16*)&hb2[s][0])[u] = hv;
      ((_Float16*)&dech2[s][t][0])[u] = hv;
    }
    __syncthreads();
  }

  // ----------------- head -----------------
  {
    int j = tid & 63, w = tid >> 6;       // w in 0..15; st = w + 16*m
    float acc[4];
    #pragma unroll
    for (int m = 0; m < 4; ++m) acc[m] = b1[j];
    #pragma unroll 8
    for (int k = 0; k < 64; ++k) {
      uint32_t wv = W1h[k*64 + j];
      #pragma unroll
      for (int m = 0; m < 4; ++m) {
        int st = w + 16*m;
        acc[m] = fdot2_(wv, dech2[st >> 5][st & 31][k], acc[m]);
      }
    }
    #pragma unroll
    for (int m = 0; m < 4; ++m)
      hidf[w + 16*m][j] = fmaxf(acc[m], 0.0f);
  }
  __syncthreads();
  if (tid < 128) {
    int st = tid >> 1, e = tid & 1;
    float acc = b2[e];
    #pragma unroll 16
    for (int j = 0; j < 64; ++j) acc += W2[e*64 + j] * hidf[st][j];
    int s = st >> 5, t = st & 31;
    out_kp[((bn0 + s)*32 + t)*2 + e] = acc;
  }
}

// ---------------------------------------------------------------------------
// Launch
// ---------------------------------------------------------------------------
extern "C" void kernel_launch(void* const* d_in, const int* in_sizes, int n_in,
                              void* d_out, int out_size, void* d_ws, size_t ws_size,
                              hipStream_t stream) {
  const float* x          = (const float*)d_in[0];
  const float* mask_point = (const float*)d_in[1];
  const int*   point_mask = (const int*)d_in[2];
  const float* conv1_w    = (const float*)d_in[3];
  const float* conv1_b    = (const float*)d_in[4];
  const float* conv2_w    = (const float*)d_in[5];
  const float* conv2_b    = (const float*)d_in[6];
  const float* Wih_e      = (const float*)d_in[7];
  const float* Whh_e      = (const float*)d_in[8];
  const float* bih_e      = (const float*)d_in[9];
  const float* bhh_e      = (const float*)d_in[10];
  const float* Wih_d      = (const float*)d_in[11];
  const float* Whh_d      = (const float*)d_in[12];
  const float* bih_d      = (const float*)d_in[13];
  const float* bhh_d      = (const float*)d_in[14];
  const float* W1         = (const float*)d_in[15];
  const float* b1         = (const float*)d_in[16];
  const float* W2         = (const float*)d_in[17];
  const float* b2         = (const float*)d_in[18];

  float* out = (float*)d_out;
  char*  ws  = (char*)d_ws;

  const bool use_xt = (ws_size >= WS_NEED_XT);
  // gx overlays the xT region (dead after conv_gather); fallback area otherwise
  _Float16* gx = (_Float16*)(ws + (use_xt ? OFF_XT : OFF_GX_FB));

  prep_kernel<<<(PREP_TOTAL + 255)/256, 256, 0, stream>>>(
      Wih_e, Whh_e, bih_e, bhh_e, Wih_d, Whh_d, bih_d, bhh_d,
      conv1_w, conv2_w, W1, ws, use_xt ? 1 : 0);

  points_kernel<<<64, 256, 0, stream>>>(
      mask_point, out + 32768, (int*)(ws + OFF_FLAT));

  if (use_xt) {
    transpose_kernel<<<1024, 256, 0, stream>>>(x, (uint32_t*)(ws + OFF_XT));
    conv_gather_kernel<1><<<512, 256, 0, stream>>>(
        x, (const uint32_t*)(ws + OFF_XT), point_mask, conv1_b, conv2_b,
        ws, (_Float16*)(ws + OFF_DOTS), (const int*)(ws + OFF_FLAT));
  } else {
    conv_gather_kernel<0><<<512, 256, 0, stream>>>(
        x, nullptr, point_mask, conv1_b, conv2_b,
        ws, (_Float16*)(ws + OFF_DOTS), (const int*)(ws + OFF_FLAT));
  }

  gx_gemm_kernel<<<512, 512, 0, stream>>>(ws, gx);

  lstm_head_kernel<<<256, 1024, 0, stream>>>(
      ws, gx, b1, W2, b2, out);
}

// Round 5
// 172.753 us; speedup vs baseline: 1.0743x; 1.0743x over previous
//
#include <hip/hip_runtime.h>
#include <stdint.h>

// ---------------------------------------------------------------------------
// Problem constants
// ---------------------------------------------------------------------------
#define NSEQ 512        // B*N
#define HIDN 128

// ws byte offsets
#define OFF_PWIH_E 0
#define OFF_PWHH_E (OFF_PWIH_E + 32*512*4)      //  65536
#define OFF_PWIH_D (OFF_PWHH_E + 64*512*4)      // 196608
#define OFF_PWHH_D (OFF_PWIH_D + 64*512*4)      // 327680
#define OFF_BIAS_E (OFF_PWHH_D + 64*512*4)      // 458752
#define OFF_BIAS_D (OFF_BIAS_E + 512*4)         // 460800
#define OFF_W1P    (OFF_BIAS_D + 512*4)         // 462848  conv w1 f16 pairs [288][64]
#define OFF_W2P    (OFF_W1P + 288*64*4)         // 536576  conv w2 f16 pairs [32][64]
#define OFF_FLAT   (OFF_W2P + 32*64*4)          // 544768  [16384] int
#define OFF_W1H    (OFF_FLAT + 16384*4)         // 610304  head W1 f16 pairs [64][64]
#define OFF_FEHH   655360                       // enc Whh MFMA frags, 128 KB
#define OFF_FDIH   786432                       // dec Wih MFMA frags, 128 KB
#define OFF_FDHH   917504                       // dec Whh MFMA frags, 128 KB
#define OFF_DOTS   (1024*1024)                  // [32][512][64] f16 = 2 MB
#define OFF_XT     (4*1024*1024)                // xT [16][128][128][64] f16 = 33.5 MB
#define OFF_GX_FB  (3*1024*1024)                // fallback gx area (no-xT path)
#define WS_NEED_XT ((size_t)(4*1024*1024) + (size_t)16*128*128*64*2 + 1024)

typedef _Float16 h2f __attribute__((ext_vector_type(2)));
typedef _Float16 f16x8 __attribute__((ext_vector_type(8)));
typedef float    f32x4 __attribute__((ext_vector_type(4)));

static __device__ __forceinline__ h2f u2h(uint32_t u) {
  union { uint32_t u; h2f h; } v; v.u = u; return v.h;
}

#if __has_builtin(__builtin_amdgcn_fdot2)
static __device__ __forceinline__ float fdot2_(uint32_t a, uint32_t b, float c) {
  return __builtin_amdgcn_fdot2(u2h(a), u2h(b), c, false);
}
#else
static __device__ __forceinline__ float fdot2_(uint32_t a, uint32_t b, float c) {
  h2f x = u2h(a), y = u2h(b);
  return c + (float)x.x * (float)y.x + (float)x.y * (float)y.y;
}
#endif

static __device__ __forceinline__ uint32_t packh(float a, float b) {
  union { _Float16 h[2]; uint32_t u; } v;
  v.h[0] = (_Float16)a; v.h[1] = (_Float16)b; return v.u;
}
static __device__ __forceinline__ float sig_(float x) {
  return 1.0f / (1.0f + __expf(-x));
}
static __device__ __forceinline__ float tanh_(float x) {
  return 1.0f - 2.0f / (1.0f + __expf(2.0f * x));
}

// ---------------------------------------------------------------------------
// Kernel 0: weight prep (transpose + f16 pack + bias sums + MFMA frags)
// MFMA A-frag order for 16x16x32_f16: lane l holds A[row=l&15][k=(l>>4)*8+j],
// stored as frag[(gt*4+kt)*64 + lane] of 4 u32 (j pairs).
// ---------------------------------------------------------------------------
__global__ __launch_bounds__(256) void prep_kernel(
    const float* Wih_e, const float* Whh_e,
    const float* bih_e, const float* bhh_e,
    const float* Wih_d, const float* Whh_d,
    const float* bih_d, const float* bhh_d,
    const float* w1, const float* w2, const float* W1, char* ws, int w1_order) {
  uint32_t* pWih_e = (uint32_t*)(ws + OFF_PWIH_E);
  float*    bias_e = (float*)(ws + OFF_BIAS_E);
  float*    bias_d = (float*)(ws + OFF_BIAS_D);
  uint32_t* w1p    = (uint32_t*)(ws + OFF_W1P);
  uint32_t* w2p    = (uint32_t*)(ws + OFF_W2P);
  uint32_t* W1h    = (uint32_t*)(ws + OFF_W1H);

  int idx = blockIdx.x * 256 + threadIdx.x;
  if (idx < 32*512) {                             // pWih_e [k2][g], in=64 (for gx)
    int k2 = idx >> 9, g = idx & 511;
    pWih_e[idx] = packh(Wih_e[g*64 + 2*k2], Wih_e[g*64 + 2*k2 + 1]);
    return;
  }
  idx -= 32*512;
  if (idx < 512) { bias_e[idx] = bih_e[idx] + bhh_e[idx]; return; }
  idx -= 512;
  if (idx < 512) { bias_d[idx] = bih_d[idx] + bhh_d[idx]; return; }
  idx -= 512;
  if (idx < 288*64) {                             // conv w1 pairs [i2][c]
    int i2 = idx >> 6, c = idx & 63;
    if (w1_order) {
      int tap = i2 >> 5, cin = (i2 & 31) * 2;     // i2 = tap*32 + c2
      w1p[idx] = packh(w1[c*576 + cin*9 + tap], w1[c*576 + (cin+1)*9 + tap]);
    } else {
      w1p[idx] = packh(w1[c*576 + 2*i2], w1[c*576 + 2*i2 + 1]);
    }
    return;
  }
  idx -= 288*64;
  if (idx < 32*64) {                              // conv w2 pairs [c2][d]
    int c2 = idx >> 6, d = idx & 63;
    w2p[idx] = packh(w2[d*64 + 2*c2], w2[d*64 + 2*c2 + 1]);
    return;
  }
  idx -= 32*64;
  if (idx < 64*64) {                              // head W1 pairs [k2][j]
    int k2 = idx >> 6, j = idx & 63;
    W1h[idx] = packh(W1[j*128 + 2*k2], W1[j*128 + 2*k2 + 1]);
    return;
  }
  idx -= 64*64;
  if (idx < 3*32768) {                            // MFMA weight fragments
    int which = idx >> 15, r = idx & 32767;
    int j2 = r & 3, lane = (r >> 2) & 63, kt = (r >> 8) & 3, gt = r >> 10;
    int g = gt*16 + (lane & 15);
    int k = kt*32 + ((lane >> 4) & 3)*8 + 2*j2;
    const float* W = (which == 0) ? Whh_e : ((which == 1) ? Wih_d : Whh_d);
    uint32_t* dst = (uint32_t*)(ws + ((which == 0) ? OFF_FEHH :
                                      (which == 1) ? OFF_FDIH : OFF_FDHH));
    dst[r] = packh(W[g*128 + k], W[g*128 + k + 1]);
    return;
  }
}
#define PREP_TOTAL (32*512 + 512 + 512 + 288*64 + 32*64 + 64*64 + 3*32768)

// ---------------------------------------------------------------------------
// Kernel 1: point math -> gt (output 1) + flat indices
// ---------------------------------------------------------------------------
__global__ __launch_bounds__(256) void points_kernel(
    const float* mask_point, float* out_gt, int* flat) {
  int p = blockIdx.x * 256 + threadIdx.x;
  if (p >= 16384) return;
  float mx = mask_point[p*2 + 0];
  float my = mask_point[p*2 + 1];
  float fx = fminf(mx * 0.25f, 127.0f);
  float fy = fminf(my * 0.25f, 127.0f);
  out_gt[p*2 + 0] = fx * 4.0f;
  out_gt[p*2 + 1] = fy * 4.0f;
  flat[p] = (int)(__fmaf_rn(fy, 128.0f, fx));   // fy*128 exact -> fma == mul+add
}

// ---------------------------------------------------------------------------
// Kernel T: x [16][64][128][128] f32 -> xT [16][128][128][64] f16 (NHWC)
// ---------------------------------------------------------------------------
__global__ __launch_bounds__(256, 2) void transpose_kernel(
    const float* x, uint32_t* xT32) {
  __shared__ float lds[64][257];
  int bid = blockIdx.x;           // 1024 = 16 b x 16 yt x 4 xt
  int xt = bid & 3, yt = (bid >> 2) & 15, b = bid >> 6;
  int x0 = xt * 32, y0 = yt * 8;
  int tx = threadIdx.x & 31, ty = threadIdx.x >> 5;
  #pragma unroll 8
  for (int c = 0; c < 64; ++c)
    lds[c][ty*32 + tx] = x[((b*64 + c)*128 + (y0 + ty))*128 + (x0 + tx)];
  __syncthreads();
  #pragma unroll 8
  for (int r = 0; r < 32; ++r) {
    int i = threadIdx.x + 256*r;    // i = pos*32 + c2
    int c2 = i & 31, pos = i >> 5;
    int yy = pos >> 5, xx = pos & 31;
    float lo = lds[2*c2][yy*32 + xx], hi = lds[2*c2 + 1][yy*32 + xx];
    xT32[((b*128 + y0 + yy)*128 + (x0 + xx))*32 + c2] = packh(lo, hi);
  }
}

// ---------------------------------------------------------------------------
// Kernel 2: fused gathered conv (3x3 -> ReLU -> 1x1) at points, 4 pts/group
// ---------------------------------------------------------------------------
template <int MODE>
__global__ __launch_bounds__(256, 2) void conv_gather_kernel(
    const float* x, const uint32_t* xT32, const int* point_mask,
    const float* conv1_b, const float* conv2_b,
    const char* ws_ro, _Float16* dots_h, const int* flat) {
  __shared__ uint32_t w1s[64*291];    // 74496 B
  __shared__ uint32_t patch2[4*288];  //  4608 B
  __shared__ uint32_t tl2[4*32];      //   512 B

  const uint32_t* w1p = (const uint32_t*)(ws_ro + OFF_W1P);
  const uint32_t* w2p = (const uint32_t*)(ws_ro + OFF_W2P);
  int tid = threadIdx.x;
  for (int i = tid; i < 288*64; i += 256) {
    int i2 = i >> 6, cc = i & 63;
    w1s[cc*291 + i2] = w1p[i];
  }

  int q = tid >> 6, c = tid & 63;
  float c1b = conv1_b[c], c2b = conv2_b[c];

  for (int g = 0; g < 8; ++g) {
    int p0 = blockIdx.x * 32 + g * 4;
    __syncthreads();
    if (MODE == 1) {
      #pragma unroll
      for (int r = 0; r < 5; ++r) {  // 1152 u32 = 4 pts x 288
        int u = tid + 256*r;
        if (u < 1152) {
          int slot = u / 288, w = u - slot*288;
          int tap = w >> 5, c2i = w & 31;
          int p = p0 + slot;
          int fl = flat[p];
          int hh = fl >> 7, ww = fl & 127;
          int b = p >> 10;
          int dy = tap / 3, dx = tap - dy*3;
          int yy = hh + dy - 1, xx = ww + dx - 1;
          uint32_t v = 0u;
          if (yy >= 0 && yy < 128 && xx >= 0 && xx < 128)
            v = xT32[((b*128 + yy)*128 + xx)*32 + c2i];
          patch2[slot*288 + w] = v;
        }
      }
    } else {
      #pragma unroll
      for (int r = 0; r < 9; ++r) {  // 2304 halves = 4 pts x 576
        int l = tid + 256*r;
        int slot = l / 576;
        int within = l - slot*576;
        int cp = within / 9;
        int tap = within - cp*9;
        int p = p0 + slot;
        int fl = flat[p];
        int hh = fl >> 7, ww = fl & 127;
        int b = p >> 10;
        int yy = hh + tap/3 - 1, xx = ww + tap%3 - 1;
        float v = 0.0f;
        if (yy >= 0 && yy < 128 && xx >= 0 && xx < 128)
          v = x[((b*64 + cp)*128 + yy)*128 + xx];
        ((_Float16*)patch2)[l] = (_Float16)v;
      }
    }
    __syncthreads();

    float a0 = c1b, a1 = 0.f, a2 = 0.f, a3 = 0.f;
    int cbase = c * 291, pbase = q * 288;
    #pragma unroll 4
    for (int i2 = 0; i2 < 288; i2 += 4) {
      a0 = fdot2_(w1s[cbase + i2+0], patch2[pbase + i2+0], a0);
      a1 = fdot2_(w1s[cbase + i2+1], patch2[pbase + i2+1], a1);
      a2 = fdot2_(w1s[cbase + i2+2], patch2[pbase + i2+2], a2);
      a3 = fdot2_(w1s[cbase + i2+3], patch2[pbase + i2+3], a3);
    }
    float t1 = fmaxf((a0 + a1) + (a2 + a3), 0.0f);
    ((_Float16*)tl2)[q*64 + c] = (_Float16)t1;
    // tl2[q] written/read by same wave -> no barrier

    float acc2 = c2b;
    #pragma unroll
    for (int c2i = 0; c2i < 32; ++c2i)
      acc2 = fdot2_(w2p[c2i*64 + c], tl2[q*32 + c2i], acc2);
    int p = p0 + q;
    acc2 *= (float)point_mask[p];
    int k = p & 31, bn = p >> 5;
    dots_h[(k*NSEQ + bn)*64 + c] = (_Float16)acc2;   // time-major [k][bn][d]
  }
}

// ---------------------------------------------------------------------------
// Kernel G: encoder x-projection GEMM: gx[R][g] = bias_e[g] + Wih_e . dots[R]
// ---------------------------------------------------------------------------
__global__ __launch_bounds__(512, 4) void gx_gemm_kernel(
    const char* ws_ro, _Float16* gx) {
  const uint32_t* pWih_e = (const uint32_t*)(ws_ro + OFF_PWIH_E);
  const float*    bias_e = (const float*)(ws_ro + OFF_BIAS_E);
  const uint32_t* dots_u = (const uint32_t*)(ws_ro + OFF_DOTS);
  __shared__ uint32_t xs[32][32];   // 4 KB: 32 rows x 32 f16-pairs
  int tid = threadIdx.x;
  int R0 = blockIdx.x * 32;
  for (int i = tid; i < 32*32; i += 512)
    xs[i >> 5][i & 31] = dots_u[(R0 + (i >> 5))*32 + (i & 31)];
  uint32_t wv[32];
  #pragma unroll
  for (int k = 0; k < 32; ++k) wv[k] = pWih_e[k*512 + tid];
  float bs = bias_e[tid];
  __syncthreads();
  #pragma unroll 2
  for (int r = 0; r < 32; ++r) {
    float a = bs;
    #pragma unroll
    for (int k = 0; k < 32; ++k) a = fdot2_(wv[k], xs[r][k], a);
    gx[(size_t)(R0 + r)*512 + tid] = (_Float16)a;
  }
}

// ---------------------------------------------------------------------------
// Kernel 3: recurrent LSTMs via MFMA + batched MLP head.
// 256 blocks x 512 threads (8 waves); 2 seqs/block.
// Wave w owns gates [w*64, w*64+64) as 4 gate-tiles x 4 k-tiles of
// v_mfma_f32_16x16x32_f16 A-fragments held in registers.
// B built per step from h (f16 pairs in LDS); C cols 0,1 = the 2 seqs.
// ---------------------------------------------------------------------------
__global__ __launch_bounds__(512, 2) void lstm_head_kernel(
    const char* ws_ro, const _Float16* gx,
    const float* b1, const float* W2, const float* b2,
    float* out_kp) {
  const f16x8*    fehh   = (const f16x8*)(ws_ro + OFF_FEHH);
  const f16x8*    fdih   = (const f16x8*)(ws_ro + OFF_FDIH);
  const f16x8*    fdhh   = (const f16x8*)(ws_ro + OFF_FDHH);
  const float*    bias_d = (const float*)(ws_ro + OFF_BIAS_D);
  const uint32_t* W1h    = (const uint32_t*)(ws_ro + OFF_W1H);

  __shared__ __attribute__((aligned(16))) uint32_t enc2[2][32][64];   // 16 KB
  __shared__ __attribute__((aligned(16))) uint32_t dech2[2][32][64];  // 16 KB
  __shared__ __attribute__((aligned(16))) uint32_t hb2[2][64];        // 512 B
  __shared__ __attribute__((aligned(16))) float    gb[2][512];        //  4 KB
  __shared__ float hidf[64][65];                                      // 16.6 KB

  int tid  = threadIdx.x;
  int lane = tid & 63, wave = tid >> 6;
  int col  = lane & 15, lgrp = lane >> 4;
  int bn0  = blockIdx.x * 2;

  int s_nl = tid >> 7, u_nl = tid & 127;    // nonlinearity role (tid < 256)
  float c_reg = 0.0f;

  // encoder h-weights as MFMA fragments (16 frags = 64 VGPRs)
  f16x8 ae[4][4];
  #pragma unroll
  for (int g0 = 0; g0 < 4; ++g0)
    #pragma unroll
    for (int kt = 0; kt < 4; ++kt)
      ae[g0][kt] = fehh[((wave*4 + g0)*4 + kt)*64 + lane];

  if (tid < 128) hb2[tid >> 6][tid & 63] = 0u;
  __syncthreads();

  const f16x8 bzero = {};

  // ----------------- encoder -----------------
  for (int t = 0; t < 32; ++t) {
    // early-issue gx loads (hidden under MFMA phase)
    float gxi = 0.f, gxf = 0.f, gxg = 0.f, gxo = 0.f;
    if (tid < 256) {
      const _Float16* gr = gx + (size_t)(t*512 + bn0 + s_nl)*512;
      gxi = (float)gr[u_nl];       gxf = (float)gr[128 + u_nl];
      gxg = (float)gr[256 + u_nl]; gxo = (float)gr[384 + u_nl];
    }
    f16x8 bf[4];
    #pragma unroll
    for (int kt = 0; kt < 4; ++kt) {
      if (col < 2) bf[kt] = *(const f16x8*)&hb2[col][kt*16 + lgrp*4];
      else         bf[kt] = bzero;
    }
    #pragma unroll
    for (int g0 = 0; g0 < 4; ++g0) {
      f32x4 acc = {0.f, 0.f, 0.f, 0.f};
      #pragma unroll
      for (int kt = 0; kt < 4; ++kt)
        acc = __builtin_amdgcn_mfma_f32_16x16x32_f16(ae[g0][kt], bf[kt], acc, 0, 0, 0);
      if (col < 2)
        *(f32x4*)&gb[col][(wave*4 + g0)*16 + lgrp*4] = acc;
    }
    __syncthreads();
    if (tid < 256) {
      float ig = sig_ (gb[s_nl][u_nl]       + gxi);
      float fg = sig_ (gb[s_nl][128 + u_nl] + gxf);
      float gg = tanh_(gb[s_nl][256 + u_nl] + gxg);
      float og = sig_ (gb[s_nl][384 + u_nl] + gxo);
      c_reg = fg * c_reg + ig * gg;
      float hh = og * tanh_(c_reg);
      _Float16 hv = (_Float16)hh;
      ((_Float16*)&hb2[s_nl][0])[u_nl] = hv;
      ((_Float16*)&enc2[s_nl][t][0])[u_nl] = hv;
    }
    __syncthreads();
  }

  // ----------------- decoder -----------------
  f16x8 ai[4][4], ah[4][4];
  #pragma unroll
  for (int g0 = 0; g0 < 4; ++g0)
    #pragma unroll
    for (int kt = 0; kt < 4; ++kt) {
      ai[g0][kt] = fdih[((wave*4 + g0)*4 + kt)*64 + lane];
      ah[g0][kt] = fdhh[((wave*4 + g0)*4 + kt)*64 + lane];
    }
  float bdi = 0.f, bdf = 0.f, bdg = 0.f, bdo = 0.f;
  if (tid < 256) {
    bdi = bias_d[u_nl];       bdf = bias_d[128 + u_nl];
    bdg = bias_d[256 + u_nl]; bdo = bias_d[384 + u_nl];
  }

  for (int t = 0; t < 32; ++t) {
    f16x8 bx[4], bh[4];
    #pragma unroll
    for (int kt = 0; kt < 4; ++kt) {
      if (col < 2) {
        bx[kt] = *(const f16x8*)&enc2[col][t][kt*16 + lgrp*4];
        bh[kt] = *(const f16x8*)&hb2[col][kt*16 + lgrp*4];
      } else { bx[kt] = bzero; bh[kt] = bzero; }
    }
    #pragma unroll
    for (int g0 = 0; g0 < 4; ++g0) {
      f32x4 acc = {0.f, 0.f, 0.f, 0.f};
      #pragma unroll
      for (int kt = 0; kt < 4; ++kt)
        acc = __builtin_amdgcn_mfma_f32_16x16x32_f16(ai[g0][kt], bx[kt], acc, 0, 0, 0);
      #pragma unroll
      for (int kt = 0; kt < 4; ++kt)
        acc = __builtin_amdgcn_mfma_f32_16x16x32_f16(ah[g0][kt], bh[kt], acc, 0, 0, 0);
      if (col < 2)
        *(f32x4*)&gb[col][(wave*4 + g0)*16 + lgrp*4] = acc;
    }
    __syncthreads();
    if (tid < 256) {
      float ig = sig_ (gb[s_nl][u_nl]       + bdi);
      float fg = sig_ (gb[s_nl][128 + u_nl] + bdf);
      float gg = tanh_(gb[s_nl][256 + u_nl] + bdg);
      float og = sig_ (gb[s_nl][384 + u_nl] + bdo);
      c_reg = fg * c_reg + ig * gg;
      float hh = og * tanh_(c_reg);
      _Float16 hv = (_Float16)hh;
      ((_Float16*)&hb2[s_nl][0])[u_nl] = hv;
      ((_Float16*)&dech2[s_nl][t][0])[u_nl] = hv;
    }
    __syncthreads();
  }

  // ----------------- head: hid = relu(dec @ W1.T + b1); y = hid @ W2.T + b2
  {
    int j = tid & 63, w = tid >> 6;       // wave handles st = w + 8*m
    float acc[8];
    #pragma unroll
    for (int m = 0; m < 8; ++m) acc[m] = b1[j];
    #pragma unroll 8
    for (int k = 0; k < 64; ++k) {
      uint32_t wv = W1h[k*64 + j];
      #pragma unroll
      for (int m = 0; m < 8; ++m) {
        int st = w + 8*m;
        acc[m] = fdot2_(wv, dech2[st >> 5][st & 31][k], acc[m]);
      }
    }
    #pragma unroll
    for (int m = 0; m < 8; ++m) {
      int st = w + 8*m;
      hidf[st][j] = fmaxf(acc[m], 0.0f);
    }
  }
  __syncthreads();
  if (tid < 128) {
    int st = tid >> 1, e = tid & 1;
    float acc = b2[e];
    #pragma unroll 16
    for (int j = 0; j < 64; ++j) acc += W2[e*64 + j] * hidf[st][j];
    int s = st >> 5, t = st & 31;
    out_kp[((bn0 + s)*32 + t)*2 + e] = acc;
  }
}

// ---------------------------------------------------------------------------
// Launch
// ---------------------------------------------------------------------------
extern "C" void kernel_launch(void* const* d_in, const int* in_sizes, int n_in,
                              void* d_out, int out_size, void* d_ws, size_t ws_size,
                              hipStream_t stream) {
  const float* x          = (const float*)d_in[0];
  const float* mask_point = (const float*)d_in[1];
  const int*   point_mask = (const int*)d_in[2];
  const float* conv1_w    = (const float*)d_in[3];
  const float* conv1_b    = (const float*)d_in[4];
  const float* conv2_w    = (const float*)d_in[5];
  const float* conv2_b    = (const float*)d_in[6];
  const float* Wih_e      = (const float*)d_in[7];
  const float* Whh_e      = (const float*)d_in[8];
  const float* bih_e      = (const float*)d_in[9];
  const float* bhh_e      = (const float*)d_in[10];
  const float* Wih_d      = (const float*)d_in[11];
  const float* Whh_d      = (const float*)d_in[12];
  const float* bih_d      = (const float*)d_in[13];
  const float* bhh_d      = (const float*)d_in[14];
  const float* W1         = (const float*)d_in[15];
  const float* b1         = (const float*)d_in[16];
  const float* W2         = (const float*)d_in[17];
  const float* b2         = (const float*)d_in[18];

  float* out = (float*)d_out;
  char*  ws  = (char*)d_ws;

  const bool use_xt = (ws_size >= WS_NEED_XT);
  // gx overlays the xT region (dead after conv_gather); fallback area otherwise
  _Float16* gx = (_Float16*)(ws + (use_xt ? OFF_XT : OFF_GX_FB));

  prep_kernel<<<(PREP_TOTAL + 255)/256, 256, 0, stream>>>(
      Wih_e, Whh_e, bih_e, bhh_e, Wih_d, Whh_d, bih_d, bhh_d,
      conv1_w, conv2_w, W1, ws, use_xt ? 1 : 0);

  points_kernel<<<64, 256, 0, stream>>>(
      mask_point, out + 32768, (int*)(ws + OFF_FLAT));

  if (use_xt) {
    transpose_kernel<<<1024, 256, 0, stream>>>(x, (uint32_t*)(ws + OFF_XT));
    conv_gather_kernel<1><<<512, 256, 0, stream>>>(
        x, (const uint32_t*)(ws + OFF_XT), point_mask, conv1_b, conv2_b,
        ws, (_Float16*)(ws + OFF_DOTS), (const int*)(ws + OFF_FLAT));
  } else {
    conv_gather_kernel<0><<<512, 256, 0, stream>>>(
        x, nullptr, point_mask, conv1_b, conv2_b,
        ws, (_Float16*)(ws + OFF_DOTS), (const int*)(ws + OFF_FLAT));
  }

  gx_gemm_kernel<<<512, 512, 0, stream>>>(ws, gx);

  lstm_head_kernel<<<256, 512, 0, stream>>>(
      ws, gx, b1, W2, b2, out);
}